// Round 4
// baseline (1862.203 us; speedup 1.0000x reference)
//
#include <hip/hip_runtime.h>
#include <math.h>

#define BB   64
#define NIN  512
#define NH   512
#define TT   512

typedef _Float16 half2_t __attribute__((ext_vector_type(2)));

// ---------------------------------------------------------------------------
// K1: u[t][b][h] = sum_i X[b][i][t] * Wax[i][h] + bx[h] + ba[h]
// fp32, 128x128 tile per block, 8x8 per thread, 256 threads, 4 blocks/CU.
// Written directly into d_out at [t][b][h]; K2 overwrites in place.
// ---------------------------------------------------------------------------
__global__ __launch_bounds__(256) void inp_proj_kernel(
    const float* __restrict__ X, const float* __restrict__ Wax,
    const float* __restrict__ bx, const float* __restrict__ ba,
    float* __restrict__ out)
{
    __shared__ float Xs[8][128];
    __shared__ float Ws[8][128];

    const int b   = blockIdx.z;
    const int t0  = blockIdx.y * 128;
    const int h0  = blockIdx.x * 128;
    const int tid = threadIdx.x;
    const int tx  = tid & 15;          // h-subtile
    const int ty  = tid >> 4;          // t-subtile
    const int lr  = tid >> 5;          // staging row 0..7
    const int lc  = (tid & 31) * 4;    // staging col

    const float* Xb = X + (size_t)b * NIN * TT;

    float c[8][8] = {};

    for (int i0 = 0; i0 < NIN; i0 += 8) {
        *(float4*)&Xs[lr][lc] = *(const float4*)&Xb[(size_t)(i0 + lr) * TT + t0 + lc];
        *(float4*)&Ws[lr][lc] = *(const float4*)&Wax[(size_t)(i0 + lr) * NH + h0 + lc];
        __syncthreads();
#pragma unroll
        for (int k = 0; k < 8; ++k) {
            float av[8], bv[8];
            *(float4*)&av[0] = *(float4*)&Xs[k][ty * 8];
            *(float4*)&av[4] = *(float4*)&Xs[k][ty * 8 + 4];
            *(float4*)&bv[0] = *(float4*)&Ws[k][tx * 8];
            *(float4*)&bv[4] = *(float4*)&Ws[k][tx * 8 + 4];
#pragma unroll
            for (int ii = 0; ii < 8; ++ii)
#pragma unroll
                for (int jj = 0; jj < 8; ++jj)
                    c[ii][jj] = fmaf(av[ii], bv[jj], c[ii][jj]);
        }
        __syncthreads();
    }

    float bias[8];
#pragma unroll
    for (int j = 0; j < 8; ++j)
        bias[j] = bx[h0 + tx * 8 + j] + ba[h0 + tx * 8 + j];

#pragma unroll
    for (int ii = 0; ii < 8; ++ii) {
        const int t = t0 + ty * 8 + ii;
        float* orow = &out[(size_t)t * (BB * NH) + (size_t)b * NH + h0 + tx * 8];
        float4 v0, v1;
        v0.x = c[ii][0] + bias[0]; v0.y = c[ii][1] + bias[1];
        v0.z = c[ii][2] + bias[2]; v0.w = c[ii][3] + bias[3];
        v1.x = c[ii][4] + bias[4]; v1.y = c[ii][5] + bias[5];
        v1.z = c[ii][6] + bias[6]; v1.w = c[ii][7] + bias[7];
        *(float4*)&orow[0] = v0;
        *(float4*)&orow[4] = v1;
    }
}

// ---------------------------------------------------------------------------
// K2: one block per batch (64 x 512 thr). Thread (kq=tid>>7, cidx=tid&127)
// owns 4 columns {cidx*4..+3} over k in [kq*128, kq*128+128), weights as 256
// packed-fp16 pairs fully register-resident. a_t broadcast via LDS
// (ds_read_b128, wave-uniform address -> no VALU cost, 4x amortized over
// columns). 4-way k-partials reduced through LDS. Two raw s_barriers/step
// (no vmcnt drain: u-prefetch and out-store stay in flight).
// ---------------------------------------------------------------------------
#define PSTRIDE 516   // part row stride (pad: kq*516 ≡ 4*kq mod 32 -> no conflicts)

__device__ __forceinline__ unsigned pk16(float x, float y) {
    unsigned lo = (unsigned)__builtin_bit_cast(unsigned short, (_Float16)x);
    unsigned hi = (unsigned)__builtin_bit_cast(unsigned short, (_Float16)y);
    return lo | (hi << 16);
}

__device__ __forceinline__ float dot2u(unsigned w, unsigned a, float acc) {
    return __builtin_amdgcn_fdot2(__builtin_bit_cast(half2_t, w),
                                  __builtin_bit_cast(half2_t, a), acc, false);
}

__device__ __forceinline__ float tanh_fast(float x) {
    float ax = __builtin_fabsf(x);
    float e  = __builtin_amdgcn_exp2f(-2.885390082f * ax);   // exp(-2|x|)
    float r  = (1.0f - e) * __builtin_amdgcn_rcpf(1.0f + e);
    return __builtin_copysignf(r, x);
}

__global__ __launch_bounds__(512, 2) void rnn_scan_v4(
    const float* __restrict__ Waa, float* __restrict__ out)
{
    __shared__ unsigned a_lds[2][256];        // a_t as packed half2 pairs, dbl-buf
    __shared__ float    part[4][PSTRIDE];     // k-quarter partials

    const int tid  = threadIdx.x;
    const int b    = blockIdx.x;
    const int cidx = tid & 127;
    const int kq   = tid >> 7;
    const int h4   = cidx * 4;                // first of this thread's 4 columns

    // ---- preamble: load 4 columns x 64 k-pairs of Waa, convert to fp16 ----
    unsigned w0[64], w1[64], w2[64], w3[64];
#pragma unroll
    for (int j = 0; j < 64; ++j) {
        const int k = kq * 128 + 2 * j;
        float4 r0 = *(const float4*)&Waa[(size_t)k       * NH + h4];
        float4 r1 = *(const float4*)&Waa[(size_t)(k + 1) * NH + h4];
        w0[j] = pk16(r0.x, r1.x);
        w1[j] = pk16(r0.y, r1.y);
        w2[j] = pk16(r0.z, r1.z);
        w3[j] = pk16(r0.w, r1.w);
    }

    if (tid < 256) a_lds[0][tid] = 0u;        // a_0 = 0
    __syncthreads();

    float* ob = out + (size_t)b * NH + tid;   // this thread's output column h=tid
    float u_cur = ob[0];

    for (int t = 0; t < TT; ++t) {
        // prefetch next step's input projection (overlaps compute)
        const int tn = (t + 1 < TT) ? (t + 1) : (TT - 1);
        float u_next = ob[(size_t)tn * (BB * NH)];

        // ---- 256 dot2: 4 columns x 64 pairs; a via LDS broadcast ----
        const unsigned* ap = &a_lds[t & 1][kq * 64];
        float acc0 = 0.f, acc1 = 0.f, acc2 = 0.f, acc3 = 0.f;
#pragma unroll
        for (int jj = 0; jj < 16; ++jj) {
            uint4 a4 = *(const uint4*)&ap[jj * 4];
            const int j = jj * 4;
            acc0 = dot2u(w0[j + 0], a4.x, acc0);
            acc1 = dot2u(w1[j + 0], a4.x, acc1);
            acc2 = dot2u(w2[j + 0], a4.x, acc2);
            acc3 = dot2u(w3[j + 0], a4.x, acc3);
            acc0 = dot2u(w0[j + 1], a4.y, acc0);
            acc1 = dot2u(w1[j + 1], a4.y, acc1);
            acc2 = dot2u(w2[j + 1], a4.y, acc2);
            acc3 = dot2u(w3[j + 1], a4.y, acc3);
            acc0 = dot2u(w0[j + 2], a4.z, acc0);
            acc1 = dot2u(w1[j + 2], a4.z, acc1);
            acc2 = dot2u(w2[j + 2], a4.z, acc2);
            acc3 = dot2u(w3[j + 2], a4.z, acc3);
            acc0 = dot2u(w0[j + 3], a4.w, acc0);
            acc1 = dot2u(w1[j + 3], a4.w, acc1);
            acc2 = dot2u(w2[j + 3], a4.w, acc2);
            acc3 = dot2u(w3[j + 3], a4.w, acc3);
        }

        // ---- publish k-quarter partials for the 4 owned columns ----
        float4 pv; pv.x = acc0; pv.y = acc1; pv.z = acc2; pv.w = acc3;
        *(float4*)&part[kq][h4] = pv;
        __builtin_amdgcn_s_waitcnt(0xC07F);   // lgkmcnt(0)
        __builtin_amdgcn_s_barrier();         // barrier A (raw: no vmcnt drain)

        // ---- reduce across k-quarters for column h = tid ----
        float x = u_cur + ((part[0][tid] + part[1][tid]) +
                           (part[2][tid] + part[3][tid]));
        float an = tanh_fast(x);
        ob[(size_t)t * (BB * NH)] = an;       // fire-and-forget store
        u_cur = u_next;

        // ---- exchange a_{t+1} (packed fp16) into the other buffer ----
        ((unsigned short*)a_lds[(t + 1) & 1])[tid] =
            __builtin_bit_cast(unsigned short, (_Float16)an);
        __builtin_amdgcn_s_waitcnt(0xC07F);   // lgkmcnt(0)
        __builtin_amdgcn_s_barrier();         // barrier B
    }
}

extern "C" void kernel_launch(void* const* d_in, const int* in_sizes, int n_in,
                              void* d_out, int out_size, void* d_ws, size_t ws_size,
                              hipStream_t stream) {
    const float* X   = (const float*)d_in[0];
    const float* Wax = (const float*)d_in[1];
    const float* Waa = (const float*)d_in[2];
    const float* bx  = (const float*)d_in[3];
    const float* ba  = (const float*)d_in[4];
    float* out = (float*)d_out;

    dim3 g1(NH / 128, TT / 128, BB);
    inp_proj_kernel<<<g1, 256, 0, stream>>>(X, Wax, bx, ba, out);
    rnn_scan_v4<<<BB, NH, 0, stream>>>(Waa, out);
}

// Round 5
// 1100.975 us; speedup vs baseline: 1.6914x; 1.6914x over previous
//
#include <hip/hip_runtime.h>
#include <math.h>

#define BB   64
#define NIN  512
#define NH   512
#define TT   512

typedef _Float16 half2_t __attribute__((ext_vector_type(2)));

__device__ __forceinline__ unsigned pk16(float x, float y) {
    unsigned lo = (unsigned)__builtin_bit_cast(unsigned short, (_Float16)x);
    unsigned hi = (unsigned)__builtin_bit_cast(unsigned short, (_Float16)y);
    return lo | (hi << 16);
}

__device__ __forceinline__ float dot2u(unsigned w, unsigned a, float acc) {
    return __builtin_amdgcn_fdot2(__builtin_bit_cast(half2_t, w),
                                  __builtin_bit_cast(half2_t, a), acc, false);
}

__device__ __forceinline__ float tanh_fast(float x) {
    float ax = __builtin_fabsf(x);
    float e  = __builtin_amdgcn_exp2f(-2.885390082f * ax);   // exp(-2|x|)
    float r  = (1.0f - e) * __builtin_amdgcn_rcpf(1.0f + e);
    return __builtin_copysignf(r, x);
}

// ---------------------------------------------------------------------------
// K1: u[t][b][h] = sum_i X[b][i][t]*Wax[i][h] + bx[h] + ba[h], into d_out.
// fp16-dot2 inner math (fp32 accumulate), 128x128 tile, BK=16 (8 k-pairs),
// 256 threads, 8x8 accs/thread. Packing done once at staging.
// ---------------------------------------------------------------------------
__global__ __launch_bounds__(256) void inp_proj_fp16(
    const float* __restrict__ X, const float* __restrict__ Wax,
    const float* __restrict__ bx, const float* __restrict__ ba,
    float* __restrict__ out)
{
    __shared__ unsigned Xsp[8][128];   // [k-pair][t] packed half2 (k0,k1)
    __shared__ unsigned Wsp[8][128];   // [k-pair][h] packed half2

    const int b   = blockIdx.z;
    const int t0  = blockIdx.y * 128;
    const int h0  = blockIdx.x * 128;
    const int tid = threadIdx.x;
    const int tx  = tid & 15;          // h-subtile
    const int ty  = tid >> 4;          // t-subtile
    const int lr  = tid >> 5;          // staging pair-row 0..7
    const int lc  = (tid & 31) * 4;    // staging col

    const float* Xb = X + (size_t)b * NIN * TT;

    float c[8][8] = {};

    for (int i0 = 0; i0 < NIN; i0 += 16) {
        const int k0 = i0 + 2 * lr, k1 = k0 + 1;
        float4 x0 = *(const float4*)&Xb[(size_t)k0 * TT + t0 + lc];
        float4 x1 = *(const float4*)&Xb[(size_t)k1 * TT + t0 + lc];
        float4 g0 = *(const float4*)&Wax[(size_t)k0 * NH + h0 + lc];
        float4 g1 = *(const float4*)&Wax[(size_t)k1 * NH + h0 + lc];
        uint4 xp, wp;
        xp.x = pk16(x0.x, x1.x); xp.y = pk16(x0.y, x1.y);
        xp.z = pk16(x0.z, x1.z); xp.w = pk16(x0.w, x1.w);
        wp.x = pk16(g0.x, g1.x); wp.y = pk16(g0.y, g1.y);
        wp.z = pk16(g0.z, g1.z); wp.w = pk16(g0.w, g1.w);
        __syncthreads();               // protect previous iter's readers
        *(uint4*)&Xsp[lr][lc] = xp;
        *(uint4*)&Wsp[lr][lc] = wp;
        __syncthreads();
#pragma unroll
        for (int p = 0; p < 8; ++p) {
            unsigned apk[8], bpk[8];
            *(uint4*)&apk[0] = *(uint4*)&Xsp[p][ty * 8];
            *(uint4*)&apk[4] = *(uint4*)&Xsp[p][ty * 8 + 4];
            *(uint4*)&bpk[0] = *(uint4*)&Wsp[p][tx * 8];
            *(uint4*)&bpk[4] = *(uint4*)&Wsp[p][tx * 8 + 4];
#pragma unroll
            for (int ii = 0; ii < 8; ++ii)
#pragma unroll
                for (int jj = 0; jj < 8; ++jj)
                    c[ii][jj] = dot2u(bpk[jj], apk[ii], c[ii][jj]);
        }
    }

    float bias[8];
#pragma unroll
    for (int j = 0; j < 8; ++j)
        bias[j] = bx[h0 + tx * 8 + j] + ba[h0 + tx * 8 + j];

#pragma unroll
    for (int ii = 0; ii < 8; ++ii) {
        const int t = t0 + ty * 8 + ii;
        float* orow = &out[(size_t)t * (BB * NH) + (size_t)b * NH + h0 + tx * 8];
        float4 v0, v1;
        v0.x = c[ii][0] + bias[0]; v0.y = c[ii][1] + bias[1];
        v0.z = c[ii][2] + bias[2]; v0.w = c[ii][3] + bias[3];
        v1.x = c[ii][4] + bias[4]; v1.y = c[ii][5] + bias[5];
        v1.z = c[ii][6] + bias[6]; v1.w = c[ii][7] + bias[7];
        *(float4*)&orow[0] = v0;
        *(float4*)&orow[4] = v1;
    }
}

// ---------------------------------------------------------------------------
// K2: one block per batch (64 x 512 thr). Thread (kq=tid>>7, cidx=tid&127)
// owns 4 columns over its k-quarter (64 pairs/col): pairs 0..51 in VGPRs
// (208 dwords — round 3's proven budget), pairs 52..63 in LDS (96 KB,
// [48][512] layout = conflict-free). a_t broadcast via v_readlane from ONE
// wave-local register (1 ds_read_b32/step) — zero hot-loop memory latency;
// each readlane feeds 4 dot2s. k-partials reduced via LDS. Two raw
// s_barriers/step (no vmcnt drain).
// ---------------------------------------------------------------------------
#define NRP 52        // register-resident pairs per column
#define NLP 12        // LDS-resident pairs per column
#define PSTRIDE 516

__device__ __forceinline__ unsigned bline(unsigned a, int l) {
    return (unsigned)__builtin_amdgcn_readlane((int)a, l);
}

__global__ __launch_bounds__(512, 2) void rnn_scan_v5(
    const float* __restrict__ Waa, float* __restrict__ out)
{
    __shared__ unsigned wlds[NLP * 4][NH];   // 96 KB  [ (p*4+c) ][ tid ]
    __shared__ unsigned a_lds[2][256];       // packed half2 pairs, dbl-buffered
    __shared__ float    part[4][PSTRIDE];    // k-quarter partials

    const int tid  = threadIdx.x;
    const int b    = blockIdx.x;
    const int cidx = tid & 127;
    const int kq   = tid >> 7;
    const int h4   = cidx * 4;
    const int lane = tid & 63;

    // ---- preamble: 4 columns x 64 pairs; 52 -> VGPR, 12 -> LDS ----
    unsigned w0[NRP], w1[NRP], w2[NRP], w3[NRP];
#pragma unroll
    for (int j = 0; j < NRP; ++j) {
        const int k = kq * 128 + 2 * j;
        float4 r0 = *(const float4*)&Waa[(size_t)k       * NH + h4];
        float4 r1 = *(const float4*)&Waa[(size_t)(k + 1) * NH + h4];
        w0[j] = pk16(r0.x, r1.x);
        w1[j] = pk16(r0.y, r1.y);
        w2[j] = pk16(r0.z, r1.z);
        w3[j] = pk16(r0.w, r1.w);
    }
#pragma unroll
    for (int p = 0; p < NLP; ++p) {
        const int k = kq * 128 + 2 * (NRP + p);
        float4 r0 = *(const float4*)&Waa[(size_t)k       * NH + h4];
        float4 r1 = *(const float4*)&Waa[(size_t)(k + 1) * NH + h4];
        wlds[p * 4 + 0][tid] = pk16(r0.x, r1.x);
        wlds[p * 4 + 1][tid] = pk16(r0.y, r1.y);
        wlds[p * 4 + 2][tid] = pk16(r0.z, r1.z);
        wlds[p * 4 + 3][tid] = pk16(r0.w, r1.w);
    }

    if (tid < 256) a_lds[0][tid] = 0u;       // a_0 = 0
    __syncthreads();

    float* ob = out + (size_t)b * NH + tid;  // this thread's output column
    float u_cur = ob[0];

    for (int t = 0; t < TT; ++t) {
        const int tn = (t + 1 < TT) ? (t + 1) : (TT - 1);
        float u_next = ob[(size_t)tn * (BB * NH)];   // prefetch

        // wave-local a: lane l holds pair kq*64+l of a_t (packed half2)
        unsigned a_loc = a_lds[t & 1][kq * 64 + lane];

        float acc0 = 0.f, acc1 = 0.f, acc2 = 0.f, acc3 = 0.f;
#pragma unroll
        for (int j = 0; j < NRP; j += 2) {
            unsigned ra = bline(a_loc, j);
            unsigned rb = bline(a_loc, j + 1);
            acc0 = dot2u(w0[j], ra, acc0);
            acc1 = dot2u(w1[j], ra, acc1);
            acc2 = dot2u(w2[j], ra, acc2);
            acc3 = dot2u(w3[j], ra, acc3);
            acc0 = dot2u(w0[j + 1], rb, acc0);
            acc1 = dot2u(w1[j + 1], rb, acc1);
            acc2 = dot2u(w2[j + 1], rb, acc2);
            acc3 = dot2u(w3[j + 1], rb, acc3);
        }
#pragma unroll
        for (int p = 0; p < NLP; ++p) {
            unsigned ra = bline(a_loc, NRP + p);
            unsigned v0 = wlds[p * 4 + 0][tid];
            unsigned v1 = wlds[p * 4 + 1][tid];
            unsigned v2 = wlds[p * 4 + 2][tid];
            unsigned v3 = wlds[p * 4 + 3][tid];
            acc0 = dot2u(v0, ra, acc0);
            acc1 = dot2u(v1, ra, acc1);
            acc2 = dot2u(v2, ra, acc2);
            acc3 = dot2u(v3, ra, acc3);
        }

        float4 pv; pv.x = acc0; pv.y = acc1; pv.z = acc2; pv.w = acc3;
        *(float4*)&part[kq][h4] = pv;
        __builtin_amdgcn_s_waitcnt(0xC07F);   // lgkmcnt(0)
        __builtin_amdgcn_s_barrier();         // barrier A (raw)

        float x = u_cur + ((part[0][tid] + part[1][tid]) +
                           (part[2][tid] + part[3][tid]));
        float an = tanh_fast(x);
        ob[(size_t)t * (BB * NH)] = an;       // fire-and-forget store
        u_cur = u_next;

        ((unsigned short*)a_lds[(t + 1) & 1])[tid] =
            __builtin_bit_cast(unsigned short, (_Float16)an);
        __builtin_amdgcn_s_waitcnt(0xC07F);   // lgkmcnt(0)
        __builtin_amdgcn_s_barrier();         // barrier B (raw)
    }
}

extern "C" void kernel_launch(void* const* d_in, const int* in_sizes, int n_in,
                              void* d_out, int out_size, void* d_ws, size_t ws_size,
                              hipStream_t stream) {
    const float* X   = (const float*)d_in[0];
    const float* Wax = (const float*)d_in[1];
    const float* Waa = (const float*)d_in[2];
    const float* bx  = (const float*)d_in[3];
    const float* ba  = (const float*)d_in[4];
    float* out = (float*)d_out;

    dim3 g1(NH / 128, TT / 128, BB);
    inp_proj_fp16<<<g1, 256, 0, stream>>>(X, Wax, bx, ba, out);
    rnn_scan_v5<<<BB, NH, 0, stream>>>(Waa, out);
}